// Round 10
// baseline (169.261 us; speedup 1.0000x reference)
//
#include <hip/hip_runtime.h>
#include <hip/hip_bf16.h>
#include <math.h>

typedef __attribute__((ext_vector_type(8))) short bf16x8;
typedef __attribute__((ext_vector_type(4))) float f32x4;
typedef __attribute__((ext_vector_type(4))) unsigned short u16x4;

__device__ __forceinline__ float leaky(float x) { return x > 0.0f ? x : 0.01f * x; }

__device__ __forceinline__ unsigned short f2b(float f) {
    unsigned u = __builtin_bit_cast(unsigned, f);
    u += 0x7fffu + ((u >> 16) & 1u);
    return (unsigned short)(u >> 16);
}

__device__ __forceinline__ bf16x8 cvt8(float4 u0, float4 u1) {
    bf16x8 r;
    r[0] = (short)f2b(u0.x); r[1] = (short)f2b(u0.y);
    r[2] = (short)f2b(u0.z); r[3] = (short)f2b(u0.w);
    r[4] = (short)f2b(u1.x); r[5] = (short)f2b(u1.y);
    r[6] = (short)f2b(u1.z); r[7] = (short)f2b(u1.w);
    return r;
}

// ================= D1: efficient Wfuse + both HW means + zero =================
// blk [0,32):        Ws1[1024,512] = sw1 @ wsh  (32 blocks: 8 m-tiles x 4 n-tiles of 128)
// blk [32,16416):    x_mid mean -> xm_b
// blk [16416,32800): x_deep mean -> xd_b
// blk [32800,33185): zero wf[0..394240)
__global__ __launch_bounds__(256) void prep_kernel(
    const float* __restrict__ xm, const float* __restrict__ xd,
    const float* __restrict__ sw1, const float* __restrict__ wsh,
    unsigned short* __restrict__ Ws1,
    unsigned short* __restrict__ xm_b, unsigned short* __restrict__ xd_b,
    float4* __restrict__ zbase)
{
    const int blk = blockIdx.x;
    const int tid = threadIdx.x;

    if (blk < 32) {
        // Wfuse: block = (mb 0..7, nb 0..3); 4 waves, wave w owns m-frags {m0, m0+16}
        const int mb = blk >> 2, nb = blk & 3;
        const int l = tid & 63, lr = l & 15, lc = l >> 4, w = tid >> 6;
        const int m0 = mb * 128 + w * 32;
        const int n0 = nb * 128;
        const float* ap0 = sw1 + (size_t)(m0 + lr) * 2048 + lc * 8;
        const float* ap1 = ap0 + (size_t)16 * 2048;
        f32x4 acc[2][4][2];
        #pragma unroll
        for (int a = 0; a < 2; ++a)
            #pragma unroll
            for (int b = 0; b < 4; ++b)
                #pragma unroll
                for (int c = 0; c < 2; ++c) acc[a][b][c] = (f32x4){0.f,0.f,0.f,0.f};

        for (int kt = 0; kt < 2048; kt += 32) {
            bf16x8 a0 = cvt8(*(const float4*)(ap0 + kt), *(const float4*)(ap0 + kt + 4));
            bf16x8 a1 = cvt8(*(const float4*)(ap1 + kt), *(const float4*)(ap1 + kt + 4));
            #pragma unroll
            for (int nf = 0; nf < 4; ++nf) {
                bf16x8 b0, b1;
                #pragma unroll
                for (int j = 0; j < 8; ++j) {
                    const float* bp = wsh + (size_t)(kt + lc * 8 + j) * 512 + n0 + nf * 32 + lr;
                    b0[j] = (short)f2b(bp[0]);
                    b1[j] = (short)f2b(bp[16]);
                }
                acc[0][nf][0] = __builtin_amdgcn_mfma_f32_16x16x32_bf16(a0, b0, acc[0][nf][0], 0, 0, 0);
                acc[0][nf][1] = __builtin_amdgcn_mfma_f32_16x16x32_bf16(a0, b1, acc[0][nf][1], 0, 0, 0);
                acc[1][nf][0] = __builtin_amdgcn_mfma_f32_16x16x32_bf16(a1, b0, acc[1][nf][0], 0, 0, 0);
                acc[1][nf][1] = __builtin_amdgcn_mfma_f32_16x16x32_bf16(a1, b1, acc[1][nf][1], 0, 0, 0);
            }
        }
        #pragma unroll
        for (int mf = 0; mf < 2; ++mf)
            #pragma unroll
            for (int nf = 0; nf < 4; ++nf)
                #pragma unroll
                for (int p = 0; p < 2; ++p)
                    #pragma unroll
                    for (int r = 0; r < 4; ++r) {
                        int m = m0 + mf * 16 + lc * 4 + r;
                        int n = n0 + nf * 32 + p * 16 + lr;
                        Ws1[(size_t)m * 512 + n] = f2b(acc[mf][nf][p][r]);
                    }
        return;
    }
    if (blk < 16416) {
        int b2 = blk - 32;
        int lane = tid & 63, wid = tid >> 6;
        int row  = b2 * 4 + wid;
        const float4* r = (const float4*)(xm + (size_t)row * 784);
        float s = 0.0f;
        for (int i = lane; i < 196; i += 64) {
            float4 v = r[i];
            s += v.x + v.y + v.z + v.w;
        }
        #pragma unroll
        for (int off = 32; off; off >>= 1) s += __shfl_xor(s, off);
        if (lane == 0) xm_b[row] = f2b(s * (1.0f / 784.0f));
        return;
    }
    if (blk < 32800) {
        int b3 = blk - 16416;
        int sub = tid & 15, rr = tid >> 4;
        int row = b3 * 16 + rr;
        const float* base = xd + (size_t)row * 49;
        float s = base[sub] + base[sub + 16] + base[sub + 32];
        if (sub == 0) s += base[48];
        #pragma unroll
        for (int off = 8; off; off >>= 1) s += __shfl_xor(s, off);
        if (sub == 0) xd_b[row] = f2b(s * (1.0f / 49.0f));
        return;
    }
    {
        int idx = (blk - 32800) * 256 + tid;    // 385*256 = 98560 float4 = 394240 floats
        zbase[idx] = make_float4(0.f, 0.f, 0.f, 0.f);
    }
}

// ---------- gate: poll write-once FLAG (relaxed LLC load + backoff), one acquire fence ----------
__device__ __forceinline__ void gate(const int* flag) {
    if (threadIdx.x == 0) {
        while (__hip_atomic_load(flag, __ATOMIC_RELAXED, __HIP_MEMORY_SCOPE_AGENT) == 0)
            __builtin_amdgcn_s_sleep(32);
    }
    __syncthreads();
    __builtin_amdgcn_fence(__ATOMIC_ACQUIRE, "agent");
}

// ---------- done: drain writes, bump counter; LAST producer sets the flag ----------
__device__ __forceinline__ void done(int* cnt, int target, int* flag) {
    __syncthreads();
    if (threadIdx.x == 0) {
        asm volatile("s_waitcnt vmcnt(0)" ::: "memory");
        int old = __hip_atomic_fetch_add(cnt, 1, __ATOMIC_RELAXED, __HIP_MEMORY_SCOPE_AGENT);
        if (old == target - 1)
            __hip_atomic_store(flag, 1, __ATOMIC_RELAXED, __HIP_MEMORY_SCOPE_AGENT);
    }
}

// ================= shared GEMM phase (R6/R9-validated) =================
__device__ __forceinline__ void gemm_phase(
    const void* __restrict__ A, int af, int aact,
    const void* __restrict__ B, int bfB,
    float* __restrict__ C,
    int N, int K, int Kc, int k0, int n0,
    unsigned short (*Bs)[72], int tid)
{
    const int l  = tid & 63;
    const int lr = l & 15;
    const int lc = l >> 4;
    const int m0 = (tid >> 6) * 16;
    const int srow = tid >> 4;
    const int scol = (tid & 15) * 4;

    f32x4 acc0 = {0.f,0.f,0.f,0.f}, acc1 = {0.f,0.f,0.f,0.f};

    for (int kt = 0; kt < Kc; kt += 64) {
        if (!bfB) {
            float4 v = *(const float4*)((const float*)B + (size_t)(n0 + srow) * K + k0 + kt + scol);
            __syncthreads();
            Bs[srow][scol + 0] = f2b(v.x);
            Bs[srow][scol + 1] = f2b(v.y);
            Bs[srow][scol + 2] = f2b(v.z);
            Bs[srow][scol + 3] = f2b(v.w);
        } else {
            u16x4 v = *(const u16x4*)((const unsigned short*)B + (size_t)(n0 + srow) * K + k0 + kt + scol);
            __syncthreads();
            Bs[srow][scol + 0] = v.x;
            Bs[srow][scol + 1] = v.y;
            Bs[srow][scol + 2] = v.z;
            Bs[srow][scol + 3] = v.w;
        }
        __syncthreads();

        #pragma unroll
        for (int kc = 0; kc < 2; ++kc) {
            size_t aoff = (size_t)(m0 + lr) * K + k0 + kt + kc * 32 + lc * 8;
            bf16x8 a;
            if (!af) {
                a = *(const bf16x8*)((const unsigned short*)A + aoff);
            } else {
                const float* p = (const float*)A + aoff;
                float4 u0 = *(const float4*)p;
                float4 u1 = *(const float4*)(p + 4);
                if (aact) {
                    u0.x = leaky(u0.x); u0.y = leaky(u0.y);
                    u0.z = leaky(u0.z); u0.w = leaky(u0.w);
                    u1.x = leaky(u1.x); u1.y = leaky(u1.y);
                    u1.z = leaky(u1.z); u1.w = leaky(u1.w);
                }
                a = cvt8(u0, u1);
            }
            bf16x8 b0 = *(const bf16x8*)&Bs[lr][kc * 32 + lc * 8];
            bf16x8 b1 = *(const bf16x8*)&Bs[16 + lr][kc * 32 + lc * 8];
            acc0 = __builtin_amdgcn_mfma_f32_16x16x32_bf16(a, b0, acc0, 0, 0, 0);
            acc1 = __builtin_amdgcn_mfma_f32_16x16x32_bf16(a, b1, acc1, 0, 0, 0);
        }
    }

    #pragma unroll
    for (int r = 0; r < 4; ++r) {
        int m = m0 + lc * 4 + r;
        atomicAdd(&C[(size_t)m * N + n0 + lr],      acc0[r]);
        atomicAdd(&C[(size_t)m * N + n0 + 16 + lr], acc1[r]);
    }
}

// ================= D2: fused L1 + L2 + tail + finalize (768 blocks, flag gates) =================
// bid [0,256):   C2o += xd_b @ ow1^T   (N=1024,K=2048,S=8)
// bid [256,384): C2s += xm_b @ Ws1^T   (N=1024,K=512, S=4)
// bid [384,640): gated: C3{o,s} += leaky(C2{o,s}) @ {ow2,sw2}^T  (N=512,K=1024,S=8)
// bid [640,768): gated: per-sample tail; last-arriving block finalizes.
__global__ __launch_bounds__(512, 4) void fused_kernel(
    float* __restrict__ wf,
    const unsigned short* __restrict__ xm_b, const unsigned short* __restrict__ xd_b,
    const unsigned short* __restrict__ Ws1,
    const float* __restrict__ ow1, const float* __restrict__ ow2, const float* __restrict__ ow3,
    const float* __restrict__ sw2, const float* __restrict__ sw3,
    const float* __restrict__ tw1, const float* __restrict__ tw2,
    const float* __restrict__ cw1, const float* __restrict__ cw2,
    const float* __restrict__ qw1, const float* __restrict__ qw2,
    const float* __restrict__ center, const float* __restrict__ proto,
    float* __restrict__ out)
{
    __shared__ unsigned short Bs[32][72];
    __shared__ float o2r[512], s2r[512];
    __shared__ float red[2][64][4];
    __shared__ float o3s[64], s3s[64], t1s[64], c1s[64], q1s[64];
    __shared__ float tmp[4][8];
    __shared__ int flag_sh;

    float* C2o = wf;                    // [128,1024]
    float* C2s = wf + 131072;           // [128,1024]
    float* C3o = wf + 262144;           // [128,512]
    float* C3s = wf + 327680;           // [128,512]
    int*   cntL1  = (int*)(wf + 393216);        // 128B-spaced lines, all zeroed by D1
    int*   flagL1 = (int*)(wf + 393216 + 32);
    int*   cntL2  = (int*)(wf + 393216 + 64);
    int*   flagL2 = (int*)(wf + 393216 + 96);
    int*   cntT   = (int*)(wf + 393216 + 128);
    float* ce_t = wf + 393472;          // [128] x4
    float* osv  = ce_t + 128;
    float* csv  = ce_t + 256;
    float* alv  = ce_t + 384;

    const int bid = blockIdx.x;
    const int tid = threadIdx.x;

    if (bid < 256) {
        int nt = bid >> 3, s = bid & 7;
        gemm_phase(xd_b, 0, 0, ow1, 0, C2o, 1024, 2048, 256, s * 256, nt * 32, Bs, tid);
        done(cntL1, 384, flagL1);
        return;
    }
    if (bid < 384) {
        int idx = bid - 256, nt = idx >> 2, s = idx & 3;
        gemm_phase(xm_b, 0, 0, Ws1, 1, C2s, 1024, 512, 128, s * 128, nt * 32, Bs, tid);
        done(cntL1, 384, flagL1);
        return;
    }
    if (bid < 640) {
        gate(flagL1);
        int b3 = bid - 384;
        int z = b3 >> 7, idx = b3 & 127, nt = idx >> 3, s = idx & 7;
        gemm_phase(z ? (const void*)C2s : (const void*)C2o, 1, 1,
                   z ? (const void*)sw2 : (const void*)ow2, 0,
                   z ? C3s : C3o, 512, 1024, 128, s * 128, nt * 32, Bs, tid);
        done(cntL2, 256, flagL2);
        return;
    }

    // ---------------- tail ----------------
    const int b = bid - 640;
    gate(flagL2);

    {   // layer-2 activation (512 threads, 1 elem each path)
        int e = tid;
        o2r[e] = leaky(C3o[b * 512 + e]);
        s2r[e] = leaky(C3s[b * 512 + e]);
    }
    __syncthreads();
    {   // both layer-3 matvecs: p=path, o=output, q=K-quarter
        int p = tid >> 8, o = (tid >> 2) & 63, q = tid & 3;
        const float* wr = (p ? sw3 : ow3) + (size_t)o * 512 + q * 128;
        const float* xr = (p ? s2r : o2r) + q * 128;
        float acc = 0.f;
        for (int j = 0; j < 128; ++j) acc += wr[j] * xr[j];
        red[p][o][q] = acc;
    }
    __syncthreads();
    if (tid < 128) {
        int p = tid >> 6, o = tid & 63;
        float v = leaky(red[p][o][0] + red[p][o][1] + red[p][o][2] + red[p][o][3]);
        if (p) s3s[o] = v; else o3s[o] = v;
    }
    __syncthreads();

    float ce_val = 0.f;
    int o = tid;
    if (tid < 64) {
        float acc = 0.f;
        for (int j = 0; j < 64; ++j) acc += tw1[o * 128 + j] * s3s[j];
        for (int j = 0; j < 64; ++j) acc += tw1[o * 128 + 64 + j] * (s3s[j] - center[j]);
        t1s[o] = leaky(acc);
    }
    __syncthreads();
    if (tid < 64) {
        float acc = 0.f;
        for (int j = 0; j < 64; ++j) acc += tw2[o * 64 + j] * t1s[j];
        float tex = leaky(acc);
        float sim[4];
        #pragma unroll
        for (int k = 0; k < 4; ++k) {
            float d = tex - proto[k * 64 + o];
            float v = d * d;
            #pragma unroll
            for (int off = 32; off; off >>= 1) v += __shfl_xor(v, off);
            sim[k] = v;
        }
        int cat = 0; float best = sim[0];
        #pragma unroll
        for (int k = 1; k < 4; ++k) if (sim[k] > best) { best = sim[k]; cat = k; }
        float sume = 0.f;
        #pragma unroll
        for (int k = 0; k < 4; ++k) sume += expf(sim[k] - best);
        ce_val = logf(sume);
        float acc2 = 0.f;
        for (int j = 0; j < 64; ++j) acc2 += cw1[o * 128 + j] * o3s[j];
        for (int j = 0; j < 64; ++j) acc2 += cw1[o * 128 + 64 + j] * (o3s[j] - proto[cat * 64 + j]);
        c1s[o] = leaky(acc2);
        acc2 = 0.f;
        for (int j = 0; j < 64; ++j) acc2 += qw1[o * 64 + j] * o3s[j];
        q1s[o] = leaky(acc2);
    }
    __syncthreads();
    if (tid < 64) {
        float acc = 0.f;
        for (int j = 0; j < 64; ++j) acc += cw2[o * 64 + j] * c1s[j];
        float cf = leaky(acc);
        float dc = cf - center[o];
        float cs = dc * dc;
        #pragma unroll
        for (int off = 32; off; off >>= 1) cs += __shfl_xor(cs, off);
        acc = 0.f;
        for (int j = 0; j < 64; ++j) acc += qw2[o * 64 + j] * q1s[j];
        float qf = leaky(acc);
        float dq = qf - center[o];
        float os = dq * dq;
        #pragma unroll
        for (int off = 32; off; off >>= 1) os += __shfl_xor(os, off);
        if (o == 0) {
            __hip_atomic_store(&ce_t[b], ce_val, __ATOMIC_RELAXED, __HIP_MEMORY_SCOPE_AGENT);
            __hip_atomic_store(&osv[b],  os,     __ATOMIC_RELAXED, __HIP_MEMORY_SCOPE_AGENT);
            __hip_atomic_store(&csv[b],  cs,     __ATOMIC_RELAXED, __HIP_MEMORY_SCOPE_AGENT);
            __hip_atomic_store(&alv[b],  fabsf(os - cs), __ATOMIC_RELAXED, __HIP_MEMORY_SCOPE_AGENT);
        }
    }
    __syncthreads();
    if (tid == 0) {
        asm volatile("s_waitcnt vmcnt(0)" ::: "memory");
        int old = __hip_atomic_fetch_add(cntT, 1, __ATOMIC_ACQ_REL, __HIP_MEMORY_SCOPE_AGENT);
        flag_sh = (old == 127);
    }
    __syncthreads();
    if (flag_sh) {
        float v0 = 0.f, v1 = 0.f, v2 = 0.f, v3 = 0.f;
        if (tid < 128) {
            v0 = __hip_atomic_load(&ce_t[tid], __ATOMIC_RELAXED, __HIP_MEMORY_SCOPE_AGENT);
            v1 = __hip_atomic_load(&osv[tid],  __ATOMIC_RELAXED, __HIP_MEMORY_SCOPE_AGENT);
            v2 = __hip_atomic_load(&csv[tid],  __ATOMIC_RELAXED, __HIP_MEMORY_SCOPE_AGENT);
            v3 = __hip_atomic_load(&alv[tid],  __ATOMIC_RELAXED, __HIP_MEMORY_SCOPE_AGENT);
        }
        float v[4] = { v0, v1, v2, v3 };
        int lane = tid & 63, wv = tid >> 6;
        #pragma unroll
        for (int i = 0; i < 4; ++i) {
            float x = v[i];
            #pragma unroll
            for (int off = 32; off; off >>= 1) x += __shfl_xor(x, off);
            if (lane == 0) tmp[i][wv] = x;
        }
        __syncthreads();
        if (tid < 4) {
            float s = 0.f;
            #pragma unroll
            for (int j = 0; j < 8; ++j) s += tmp[tid][j];
            out[tid] = s * (1.0f / 128.0f);
        }
    }
}

// ================= launcher =================
extern "C" void kernel_launch(void* const* d_in, const int* in_sizes, int n_in,
                              void* d_out, int out_size, void* d_ws, size_t ws_size,
                              hipStream_t stream)
{
    const float* x_mid     = (const float*)d_in[0];
    const float* x_deep    = (const float*)d_in[1];
    const float* w_shallow = (const float*)d_in[2];
    const float* ow1 = (const float*)d_in[3];
    const float* ow2 = (const float*)d_in[4];
    const float* ow3 = (const float*)d_in[5];
    const float* sw1 = (const float*)d_in[6];
    const float* sw2 = (const float*)d_in[7];
    const float* sw3 = (const float*)d_in[8];
    const float* tw1 = (const float*)d_in[9];
    const float* tw2 = (const float*)d_in[10];
    const float* cw1 = (const float*)d_in[11];
    const float* cw2 = (const float*)d_in[12];
    const float* qw1 = (const float*)d_in[13];
    const float* qw2 = (const float*)d_in[14];
    const float* center = (const float*)d_in[15];
    const float* proto  = (const float*)d_in[16];
    float* out = (float*)d_out;

    float* wf = (float*)d_ws;
    // zero region: wf[0 .. 394240)  (C2o,C2s,C3o,C3s, counters/flags, ce_t..alv)
    unsigned short* Ws1  = (unsigned short*)(wf + 394240);      // [1024,512] bf16
    unsigned short* xm_b = Ws1 + 524288;                        // [128,512]
    unsigned short* xd_b = xm_b + 65536;                        // [128,2048]

    // D1: Wfuse(32) + mid means(16384) + deep means(16384) + zero(385) = 33185 blocks
    prep_kernel<<<33185, 256, 0, stream>>>(x_mid, x_deep, sw1, w_shallow,
                                           Ws1, xm_b, xd_b, (float4*)wf);

    // D2: fused L1+L2+tail+finalize (768 blocks, all resident at 4 blocks/CU)
    fused_kernel<<<768, 512, 0, stream>>>(wf, xm_b, xd_b, Ws1,
                                          ow1, ow2, ow3, sw2, sw3,
                                          tw1, tw2, cw1, cw2, qw1, qw2,
                                          center, proto, out);
}